// Round 1
// baseline (193.332 us; speedup 1.0000x reference)
//
#include <hip/hip_runtime.h>
#include <hip/hip_fp16.h>

// NCC loss, v8: two-pass, centered-fp16 intermediates.
// v7 counters: pass1 73us, FETCH 148MB (1.875x halo), WRITE 96MB, VALU 32%,
// HBM 43%, occ 75% -> nothing saturated; LDS-read pipe ~45% of block budget.
// v8: pass1 32x24 tile (1.667x halo, stage A uses all 256 threads), stage B
// h-triple outputs (11 tap rows / 3 outputs), packed ws planes:
//   ws01 = half2(I,J), ws23 = half2(II,JJ), ws4 = half(IJ)
// -> 3 stores/output (was 5), pass2 3 loads/slice (was 5). Pass2 P2CH 40->20
// for 2x occupancy (latency-bound at 960 blocks). memset dispatch removed
// (pass1 block0 zeroes out).
#define ND 2
#define DD 160
#define HH 192
#define WW 160
#define HW (HH * WW)
#define DHW (DD * HH * WW)
#define VOX (ND * DHW)          // 9,830,400 voxels per field

__device__ __forceinline__ void slide4(const float x[12], float S[4]) {
    float f = ((x[0] + x[1]) + (x[2] + x[3]))
            + ((x[4] + x[5]) + (x[6] + x[7])) + x[8];
    S[0] = f;
    f += x[9]  - x[0]; S[1] = f;
    f += x[10] - x[1]; S[2] = f;
    f += x[11] - x[2]; S[3] = f;
}

// ---------------------------------------------------------------------------
// Pass 1: per (n,d) slice, 32x24 output tile. Stage A (256 threads = 32 halo
// rows x 8 groups): W-sums of 5 centered products. Stage B: h-triple outputs,
// packed fp16 stores.
// ---------------------------------------------------------------------------
constexpr int P1TW  = 32;
constexpr int P1TH  = 24;
constexpr int P1HLO = P1TH + 8;   // 32 rows incl. H halo

__global__ __launch_bounds__(256)
void ncc_pass1(const float* __restrict__ I, const float* __restrict__ J,
               __half2* __restrict__ ws01, __half2* __restrict__ ws23,
               __half* __restrict__ ws4, float* __restrict__ outp)
{
    __shared__ float4 sws[P1HLO][P1TW + 1];  // centered (I,J,II,JJ) W-sums
    __shared__ float  sw4[P1HLO][P1TW + 1];  // centered IJ W-sums

    const int tid = threadIdx.x;
    const int w0  = blockIdx.x * P1TW;       // 0..128
    const int h0  = blockIdx.y * P1TH;       // 0..168
    const int z   = blockIdx.z;              // n*DD + d, 0..319
    const int sbase = z * HW;

    if (tid == 0 && blockIdx.x == 0 && blockIdx.y == 0 && blockIdx.z == 0)
        *outp = 0.f;                          // replaces the memset dispatch

    // ---- stage A: 256 jobs = 32 rows x 8 groups of 4 outputs ----
    {
        const int arow = tid >> 3;           // 0..31
        const int ag   = tid & 7;            // 0..7
        const int agh  = h0 + arow - 4;
        const bool ahok = (agh >= 0) && (agh < HH);
        const int rbase = sbase + agh * WW;
        const int agws  = w0 + ag * 4 - 4;

        float a[12], b[12];
        #pragma unroll
        for (int c = 0; c < 3; ++c) {
            const int gw = agws + 4 * c;
            float4 va = make_float4(0.f, 0.f, 0.f, 0.f), vb = va;
            if (ahok && gw >= 0 && gw < WW) {
                va = *(const float4*)(I + rbase + gw);
                vb = *(const float4*)(J + rbase + gw);
                va.x -= 0.5f; va.y -= 0.5f; va.z -= 0.5f; va.w -= 0.5f;
                vb.x -= 0.5f; vb.y -= 0.5f; vb.z -= 0.5f; vb.w -= 0.5f;
            }
            *(float4*)&a[4 * c] = va;
            *(float4*)&b[4 * c] = vb;
        }
        float S0[4], S1[4], S2[4], S3[4], S4[4], f[12];
        slide4(a, S0);
        slide4(b, S1);
        #pragma unroll
        for (int i = 0; i < 12; ++i) f[i] = a[i] * a[i];
        slide4(f, S2);
        #pragma unroll
        for (int i = 0; i < 12; ++i) f[i] = b[i] * b[i];
        slide4(f, S3);
        #pragma unroll
        for (int i = 0; i < 12; ++i) f[i] = a[i] * b[i];
        slide4(f, S4);
        #pragma unroll
        for (int t = 0; t < 4; ++t) {
            sws[arow][ag * 4 + t] = make_float4(S0[t], S1[t], S2[t], S3[t]);
            sw4[arow][ag * 4 + t] = S4[t];
        }
    }
    __syncthreads();

    // ---- stage B: h-triple of outputs per thread, 11 tap rows ----
    const int oh3 = tid >> 5;                // 0..7
    const int h   = oh3 * 3;                 // 0,3,..,21
    const int ow  = tid & 31;                // 0..31
    float t0, t1, t2, t3, t4;
    float r0x, r0y, r0z, r0w, r04;           // tap row h   (for row h+1 diff)
    float r1x, r1y, r1z, r1w, r14;           // tap row h+1 (for row h+2 diff)
    {
        const float4 v = sws[h][ow];
        r0x = v.x; r0y = v.y; r0z = v.z; r0w = v.w;
        r04 = sw4[h][ow];
        t0 = r0x; t1 = r0y; t2 = r0z; t3 = r0w; t4 = r04;
    }
    {
        const float4 v = sws[h + 1][ow];
        r1x = v.x; r1y = v.y; r1z = v.z; r1w = v.w;
        r14 = sw4[h + 1][ow];
        t0 += r1x; t1 += r1y; t2 += r1z; t3 += r1w; t4 += r14;
    }
    #pragma unroll
    for (int q = 2; q < 9; ++q) {
        const float4 v = sws[h + q][ow];
        t0 += v.x; t1 += v.y; t2 += v.z; t3 += v.w;
        t4 += sw4[h + q][ow];
    }
    float u0, u1, u2, u3, u4;
    {
        const float4 v = sws[h + 9][ow];
        u0 = t0 + v.x - r0x;
        u1 = t1 + v.y - r0y;
        u2 = t2 + v.z - r0z;
        u3 = t3 + v.w - r0w;
        u4 = t4 + sw4[h + 9][ow] - r04;
    }
    float v0, v1, v2, v3, v4;
    {
        const float4 v = sws[h + 10][ow];
        v0 = u0 + v.x - r1x;
        v1 = u1 + v.y - r1y;
        v2 = u2 + v.z - r1z;
        v3 = u3 + v.w - r1w;
        v4 = u4 + sw4[h + 10][ow] - r14;
    }
    const int g = sbase + (h0 + h) * WW + (w0 + ow);
    __half2 p;
    p.x = __float2half(t0); p.y = __float2half(t1); ws01[g] = p;
    p.x = __float2half(t2); p.y = __float2half(t3); ws23[g] = p;
    ws4[g] = __float2half(t4);
    p.x = __float2half(u0); p.y = __float2half(u1); ws01[g + WW] = p;
    p.x = __float2half(u2); p.y = __float2half(u3); ws23[g + WW] = p;
    ws4[g + WW] = __float2half(u4);
    p.x = __float2half(v0); p.y = __float2half(v1); ws01[g + 2 * WW] = p;
    p.x = __float2half(v2); p.y = __float2half(v3); ws23[g + 2 * WW] = p;
    ws4[g + 2 * WW] = __float2half(v4);
}

// ---------------------------------------------------------------------------
// Pass 2: per (n,h,w) column, stream D with a 9-slot register ring. No LDS,
// no barriers. 3 packed loads per slice. Reconstruct uncentered sums, cc,
// atomic reduce.
// ---------------------------------------------------------------------------
constexpr int P2CH = 20;                    // output d's per block
constexpr int P2NS = P2CH + 8;              // 28 slices streamed

__global__ __launch_bounds__(256)
void ncc_pass2(const __half2* __restrict__ ws01, const __half2* __restrict__ ws23,
               const __half* __restrict__ ws4, float* __restrict__ outp)
{
    const int col = blockIdx.x * 256 + threadIdx.x;   // 0..61439
    const int d0  = blockIdx.y * P2CH;
    const int n   = col / HW;
    const int rem = col - n * HW;
    const int h   = rem / WW;
    const int w   = rem - h * WW;
    const int base = n * DHW + rem;

    const float cW = (float)(min(w + 4, WW - 1) - max(w - 4, 0) + 1);
    const float cH = (float)(min(h + 4, HH - 1) - max(h - 4, 0) + 1);
    const float cHW = cW * cH;

    float ring[5][9];
    #pragma unroll
    for (int p = 0; p < 5; ++p)
        #pragma unroll
        for (int q = 0; q < 9; ++q) ring[p][q] = 0.f;
    float run0 = 0.f, run1 = 0.f, run2 = 0.f, run3 = 0.f, run4 = 0.f;
    float acc = 0.f;
    const float inv = 1.0f / 729.0f;

    #pragma unroll 1
    for (int g = 0; g < 4; ++g) {           // 4 x 9 = 36 >= P2NS
        #pragma unroll
        for (int jj = 0; jj < 9; ++jj) {
            const int s = g * 9 + jj;
            if (s < P2NS) {
                const int dd = d0 - 4 + s;
                float v0 = 0.f, v1 = 0.f, v2 = 0.f, v3 = 0.f, v4 = 0.f;
                if (dd >= 0 && dd < DD) {
                    const int a = base + dd * HW;
                    const __half2 x01 = ws01[a];
                    const __half2 x23 = ws23[a];
                    v0 = __half2float(x01.x);
                    v1 = __half2float(x01.y);
                    v2 = __half2float(x23.x);
                    v3 = __half2float(x23.y);
                    v4 = __half2float(ws4[a]);
                }
                run0 += v0 - ring[0][jj]; ring[0][jj] = v0;
                run1 += v1 - ring[1][jj]; ring[1][jj] = v1;
                run2 += v2 - ring[2][jj]; ring[2][jj] = v2;
                run3 += v3 - ring[3][jj]; ring[3][jj] = v3;
                run4 += v4 - ring[4][jj]; ring[4][jj] = v4;

                if (s >= 8) {
                    const int d = d0 + s - 8;
                    const float cD  = (float)(min(d + 4, DD - 1) - max(d - 4, 0) + 1);
                    const float cnt = cHW * cD;
                    // reconstruct uncentered box sums (exact algebra)
                    const float Is  = run0 + 0.5f * cnt;
                    const float Js  = run1 + 0.5f * cnt;
                    const float I2  = run2 + run0 + 0.25f * cnt;
                    const float J2  = run3 + run1 + 0.25f * cnt;
                    const float IJ  = run4 + 0.5f * (run0 + run1) + 0.25f * cnt;
                    const float uI = Is * inv, uJ = Js * inv;
                    const float cross = IJ - uI * Js;
                    const float Iv = fmaxf(I2 - uI * Is, 1e-5f);
                    const float Jv = fmaxf(J2 - uJ * Js, 1e-5f);
                    acc += cross * cross / (Iv * Jv + 1e-5f);
                }
            }
        }
    }

    // ---- block reduction, one fp32 atomic per block ----
    __shared__ float wred[4];
    #pragma unroll
    for (int off = 32; off > 0; off >>= 1)
        acc += __shfl_down(acc, off, 64);
    const int lane = threadIdx.x & 63, wid = threadIdx.x >> 6;
    if (lane == 0) wred[wid] = acc;
    __syncthreads();
    if (threadIdx.x == 0)
        atomicAdd(outp, -(wred[0] + wred[1] + wred[2] + wred[3]));
}

// ---------------------------------------------------------------------------
// Fallback (ws too small): R9's fused kernel, known-passing at ~134 us.
// ---------------------------------------------------------------------------
constexpr int FTW = 16, FTH = 16, FHLO = FTH + 8;
constexpr int FCH = 20, FNCH = DD / FCH, FNSL = FCH + 8, FNR = FNSL / 2;

__global__ __launch_bounds__(256, 4)
void ncc_fused(const float* __restrict__ I, const float* __restrict__ J,
               float* __restrict__ outp)
{
    __shared__ float4 sws[2][FHLO][FTW + 1];
    __shared__ float  sw4[2][FHLO][FTW + 1];
    __shared__ float  wred[4];

    const int tid = threadIdx.x;
    const int w0 = blockIdx.x * FTW, h0 = blockIdx.y * FTH;
    const int z = blockIdx.z, n = z / FNCH, d0 = (z % FNCH) * FCH;
    const int lane = tid & 63, wid = tid >> 6;
    const int oh = tid >> 4, ow = tid & 15;
    const bool ajob = (tid < 192);
    const int sl = tid / 96, rj = tid - sl * 96;
    const int arow = rj >> 2, awg = rj & 3;
    const int agh = h0 + arow - 4, agws = w0 + awg * 4 - 4;
    const bool ahok = (agh >= 0) && (agh < HH);

    float rbuf[5][9];
    #pragma unroll
    for (int p = 0; p < 5; ++p)
        #pragma unroll
        for (int q = 0; q < 9; ++q) rbuf[p][q] = 0.f;
    float run0 = 0.f, run1 = 0.f, run2 = 0.f, run3 = 0.f, run4 = 0.f;
    float acc = 0.f;
    const float inv = 1.0f / 729.0f;

    #pragma unroll 1
    for (int g = 0; g < 2; ++g) {
        #pragma unroll
        for (int r = 0; r < 9; ++r) {
            const int rr = g * 9 + r;
            if (rr < FNR) {
                const int s0 = 2 * rr, dd0 = d0 - 4 + s0;
                if (ajob) {
                    const int dd = dd0 + sl;
                    if (dd >= 0 && dd < DD) {
                        float a[12], b[12];
                        const int rbase = (n * DD + dd) * HW + agh * WW;
                        #pragma unroll
                        for (int c = 0; c < 3; ++c) {
                            const int gw = agws + 4 * c;
                            float4 va = make_float4(0.f, 0.f, 0.f, 0.f), vb = va;
                            if (ahok && gw >= 0 && gw < WW) {
                                va = *(const float4*)(I + rbase + gw);
                                vb = *(const float4*)(J + rbase + gw);
                            }
                            *(float4*)&a[4 * c] = va;
                            *(float4*)&b[4 * c] = vb;
                        }
                        float S0[4], S1[4], S2[4], S3[4], S4[4], f[12];
                        slide4(a, S0);
                        slide4(b, S1);
                        #pragma unroll
                        for (int i = 0; i < 12; ++i) f[i] = a[i] * a[i];
                        slide4(f, S2);
                        #pragma unroll
                        for (int i = 0; i < 12; ++i) f[i] = b[i] * b[i];
                        slide4(f, S3);
                        #pragma unroll
                        for (int i = 0; i < 12; ++i) f[i] = a[i] * b[i];
                        slide4(f, S4);
                        #pragma unroll
                        for (int t = 0; t < 4; ++t) {
                            sws[sl][arow][awg * 4 + t] =
                                make_float4(S0[t], S1[t], S2[t], S3[t]);
                            sw4[sl][arow][awg * 4 + t] = S4[t];
                        }
                    }
                }
                __syncthreads();
                #pragma unroll
                for (int half = 0; half < 2; ++half) {
                    const int ddx = dd0 + half, sx = s0 + half;
                    float t0 = 0.f, t1 = 0.f, t2 = 0.f, t3 = 0.f, t4 = 0.f;
                    if (ddx >= 0 && ddx < DD) {
                        #pragma unroll
                        for (int q = 0; q < 9; ++q) {
                            const float4 v = sws[half][oh + q][ow];
                            t0 += v.x; t1 += v.y; t2 += v.z; t3 += v.w;
                            t4 += sw4[half][oh + q][ow];
                        }
                    }
                    const int jj = (2 * r + half) % 9;
                    run0 += t0 - rbuf[0][jj]; rbuf[0][jj] = t0;
                    run1 += t1 - rbuf[1][jj]; rbuf[1][jj] = t1;
                    run2 += t2 - rbuf[2][jj]; rbuf[2][jj] = t2;
                    run3 += t3 - rbuf[3][jj]; rbuf[3][jj] = t3;
                    run4 += t4 - rbuf[4][jj]; rbuf[4][jj] = t4;
                    if (sx >= 8) {
                        const float uI = run0 * inv, uJ = run1 * inv;
                        const float cross = run4 - uI * run1;
                        const float Iv = fmaxf(run2 - uI * run0, 1e-5f);
                        const float Jv = fmaxf(run3 - uJ * run1, 1e-5f);
                        acc += cross * cross / (Iv * Jv + 1e-5f);
                    }
                }
                __syncthreads();
            }
        }
    }
    #pragma unroll
    for (int off = 32; off > 0; off >>= 1)
        acc += __shfl_down(acc, off, 64);
    if (lane == 0) wred[wid] = acc;
    __syncthreads();
    if (tid == 0)
        atomicAdd(outp, -(wred[0] + wred[1] + wred[2] + wred[3]));
}

extern "C" void kernel_launch(void* const* d_in, const int* in_sizes, int n_in,
                              void* d_out, int out_size, void* d_ws, size_t ws_size,
                              hipStream_t stream)
{
    const float* I = (const float*)d_in[0];   // y_true
    const float* J = (const float*)d_in[1];   // y_pred
    float* out = (float*)d_out;

    const size_t need = (size_t)10 * VOX;     // 98.3 MB (4+4+2 B per voxel)
    if (ws_size >= need) {
        __half2* ws01 = (__half2*)d_ws;
        __half2* ws23 = ws01 + (size_t)VOX;
        __half*  ws4  = (__half*)(ws01 + 2 * (size_t)VOX);
        dim3 g1(WW / P1TW, HH / P1TH, ND * DD);   // 5 x 8 x 320 = 12800
        ncc_pass1<<<g1, 256, 0, stream>>>(I, J, ws01, ws23, ws4, out);
        dim3 g2(ND * HW / 256, DD / P2CH);        // 240 x 8 = 1920
        ncc_pass2<<<g2, 256, 0, stream>>>(ws01, ws23, ws4, out);
    } else {
        hipMemsetAsync(out, 0, sizeof(float), stream);
        dim3 grid(WW / FTW, HH / FTH, ND * FNCH); // 10 x 12 x 16
        ncc_fused<<<grid, 256, 0, stream>>>(I, J, out);
    }
}

// Round 2
// 180.510 us; speedup vs baseline: 1.0710x; 1.0710x over previous
//
#include <hip/hip_runtime.h>
#include <hip/hip_fp16.h>

// NCC loss, v9: two-pass, centered-fp16 intermediates.
// v8 post-mortem: pass1 matched prediction (59.9us, FETCH 130MB) but total
// regressed 189.5->193.3 -> P2CH 40->20 was a pass2 regression (blocks were
// already fully co-resident at 960; doubling them only added warmup work).
// v9: (1) revert P2CH=40; (2) pack (I,J,II,JJ) as one 8B half4 plane ->
// pass2 2 loads/slice, pass1 2 stores/output; (3) pass1 tile 32x32
// (halo 1.5625x, stage A 320 jobs, stage B h-quad = 3 tap rows/output).
#define ND 2
#define DD 160
#define HH 192
#define WW 160
#define HW (HH * WW)
#define DHW (DD * HH * WW)
#define VOX (ND * DHW)          // 9,830,400 voxels per field

struct alignas(8) h4 { __half2 lo, hi; };

__device__ __forceinline__ void slide4(const float x[12], float S[4]) {
    float f = ((x[0] + x[1]) + (x[2] + x[3]))
            + ((x[4] + x[5]) + (x[6] + x[7])) + x[8];
    S[0] = f;
    f += x[9]  - x[0]; S[1] = f;
    f += x[10] - x[1]; S[2] = f;
    f += x[11] - x[2]; S[3] = f;
}

// ---------------------------------------------------------------------------
// Pass 1: per (n,d) slice, 32x32 output tile. Stage A (320 jobs = 40 halo
// rows x 8 groups; tid<64 run two): W-sums of 5 centered products. Stage B:
// h-quad outputs (12 tap rows / 4 outputs), packed fp16 stores.
// ---------------------------------------------------------------------------
constexpr int P1TW  = 32;
constexpr int P1TH  = 32;
constexpr int P1HLO = P1TH + 8;   // 40 rows incl. H halo

__global__ __launch_bounds__(256)
void ncc_pass1(const float* __restrict__ I, const float* __restrict__ J,
               h4* __restrict__ ws0123, __half* __restrict__ ws4,
               float* __restrict__ outp)
{
    __shared__ float4 sws[P1HLO][P1TW + 1];  // centered (I,J,II,JJ) W-sums
    __shared__ float  sw4[P1HLO][P1TW + 1];  // centered IJ W-sums

    const int tid = threadIdx.x;
    const int w0  = blockIdx.x * P1TW;       // 0..128
    const int h0  = blockIdx.y * P1TH;       // 0..160
    const int z   = blockIdx.z;              // n*DD + d, 0..319
    const int sbase = z * HW;

    if (tid == 0 && blockIdx.x == 0 && blockIdx.y == 0 && blockIdx.z == 0)
        *outp = 0.f;                          // replaces the memset dispatch

    // ---- stage A: 320 jobs = 40 rows x 8 groups of 4 outputs ----
    for (int job = tid; job < 8 * P1HLO; job += 256) {
        const int arow = job >> 3;           // 0..39
        const int ag   = job & 7;            // 0..7
        const int agh  = h0 + arow - 4;
        const bool ahok = (agh >= 0) && (agh < HH);
        const int rbase = sbase + agh * WW;
        const int agws  = w0 + ag * 4 - 4;

        float a[12], b[12];
        #pragma unroll
        for (int c = 0; c < 3; ++c) {
            const int gw = agws + 4 * c;
            float4 va = make_float4(0.f, 0.f, 0.f, 0.f), vb = va;
            if (ahok && gw >= 0 && gw < WW) {
                va = *(const float4*)(I + rbase + gw);
                vb = *(const float4*)(J + rbase + gw);
                va.x -= 0.5f; va.y -= 0.5f; va.z -= 0.5f; va.w -= 0.5f;
                vb.x -= 0.5f; vb.y -= 0.5f; vb.z -= 0.5f; vb.w -= 0.5f;
            }
            *(float4*)&a[4 * c] = va;
            *(float4*)&b[4 * c] = vb;
        }
        float S0[4], S1[4], S2[4], S3[4], S4[4], f[12];
        slide4(a, S0);
        slide4(b, S1);
        #pragma unroll
        for (int i = 0; i < 12; ++i) f[i] = a[i] * a[i];
        slide4(f, S2);
        #pragma unroll
        for (int i = 0; i < 12; ++i) f[i] = b[i] * b[i];
        slide4(f, S3);
        #pragma unroll
        for (int i = 0; i < 12; ++i) f[i] = a[i] * b[i];
        slide4(f, S4);
        #pragma unroll
        for (int t = 0; t < 4; ++t) {
            sws[arow][ag * 4 + t] = make_float4(S0[t], S1[t], S2[t], S3[t]);
            sw4[arow][ag * 4 + t] = S4[t];
        }
    }
    __syncthreads();

    // ---- stage B: h-quad of outputs per thread, 12 tap rows ----
    const int h  = (tid >> 5) * 4;           // 0,4,..,28
    const int ow = tid & 31;                 // 0..31
    float t0, t1, t2, t3, t4;
    float a0x, a0y, a0z, a0w, a04;           // tap row h   (diff for out1)
    float a1x, a1y, a1z, a1w, a14;           // tap row h+1 (diff for out2)
    float a2x, a2y, a2z, a2w, a24;           // tap row h+2 (diff for out3)
    {
        const float4 v = sws[h][ow];
        a0x = v.x; a0y = v.y; a0z = v.z; a0w = v.w; a04 = sw4[h][ow];
        t0 = a0x; t1 = a0y; t2 = a0z; t3 = a0w; t4 = a04;
    }
    {
        const float4 v = sws[h + 1][ow];
        a1x = v.x; a1y = v.y; a1z = v.z; a1w = v.w; a14 = sw4[h + 1][ow];
        t0 += a1x; t1 += a1y; t2 += a1z; t3 += a1w; t4 += a14;
    }
    {
        const float4 v = sws[h + 2][ow];
        a2x = v.x; a2y = v.y; a2z = v.z; a2w = v.w; a24 = sw4[h + 2][ow];
        t0 += a2x; t1 += a2y; t2 += a2z; t3 += a2w; t4 += a24;
    }
    #pragma unroll
    for (int q = 3; q < 9; ++q) {
        const float4 v = sws[h + q][ow];
        t0 += v.x; t1 += v.y; t2 += v.z; t3 += v.w;
        t4 += sw4[h + q][ow];
    }
    float u0, u1, u2, u3, u4;
    {
        const float4 v = sws[h + 9][ow];
        u0 = t0 + v.x - a0x;
        u1 = t1 + v.y - a0y;
        u2 = t2 + v.z - a0z;
        u3 = t3 + v.w - a0w;
        u4 = t4 + sw4[h + 9][ow] - a04;
    }
    float v0, v1, v2, v3, v4;
    {
        const float4 v = sws[h + 10][ow];
        v0 = u0 + v.x - a1x;
        v1 = u1 + v.y - a1y;
        v2 = u2 + v.z - a1z;
        v3 = u3 + v.w - a1w;
        v4 = u4 + sw4[h + 10][ow] - a14;
    }
    float x0, x1, x2, x3, x4;
    {
        const float4 v = sws[h + 11][ow];
        x0 = v0 + v.x - a2x;
        x1 = v1 + v.y - a2y;
        x2 = v2 + v.z - a2z;
        x3 = v3 + v.w - a2w;
        x4 = v4 + sw4[h + 11][ow] - a24;
    }
    const int g = sbase + (h0 + h) * WW + (w0 + ow);
    h4 p;
    p.lo = __floats2half2_rn(t0, t1); p.hi = __floats2half2_rn(t2, t3);
    ws0123[g] = p;             ws4[g] = __float2half(t4);
    p.lo = __floats2half2_rn(u0, u1); p.hi = __floats2half2_rn(u2, u3);
    ws0123[g + WW] = p;        ws4[g + WW] = __float2half(u4);
    p.lo = __floats2half2_rn(v0, v1); p.hi = __floats2half2_rn(v2, v3);
    ws0123[g + 2 * WW] = p;    ws4[g + 2 * WW] = __float2half(v4);
    p.lo = __floats2half2_rn(x0, x1); p.hi = __floats2half2_rn(x2, x3);
    ws0123[g + 3 * WW] = p;    ws4[g + 3 * WW] = __float2half(x4);
}

// ---------------------------------------------------------------------------
// Pass 2: per (n,h,w) column, stream D with a 9-slot register ring. No LDS,
// no barriers. 2 packed loads per slice (8B + 2B). Reconstruct uncentered
// sums, cc, atomic reduce.
// ---------------------------------------------------------------------------
constexpr int P2CH = 40;                    // output d's per block
constexpr int P2NS = P2CH + 8;              // 48 slices streamed

__global__ __launch_bounds__(256)
void ncc_pass2(const h4* __restrict__ ws0123, const __half* __restrict__ ws4,
               float* __restrict__ outp)
{
    const int col = blockIdx.x * 256 + threadIdx.x;   // 0..61439
    const int d0  = blockIdx.y * P2CH;
    const int n   = col / HW;
    const int rem = col - n * HW;
    const int h   = rem / WW;
    const int w   = rem - h * WW;
    const int base = n * DHW + rem;

    const float cW = (float)(min(w + 4, WW - 1) - max(w - 4, 0) + 1);
    const float cH = (float)(min(h + 4, HH - 1) - max(h - 4, 0) + 1);
    const float cHW = cW * cH;

    float ring[5][9];
    #pragma unroll
    for (int p = 0; p < 5; ++p)
        #pragma unroll
        for (int q = 0; q < 9; ++q) ring[p][q] = 0.f;
    float run0 = 0.f, run1 = 0.f, run2 = 0.f, run3 = 0.f, run4 = 0.f;
    float acc = 0.f;
    const float inv = 1.0f / 729.0f;

    #pragma unroll 1
    for (int g = 0; g < 6; ++g) {           // 6 x 9 = 54 >= P2NS
        #pragma unroll
        for (int jj = 0; jj < 9; ++jj) {
            const int s = g * 9 + jj;
            if (s < P2NS) {
                const int dd = d0 - 4 + s;
                float v0 = 0.f, v1 = 0.f, v2 = 0.f, v3 = 0.f, v4 = 0.f;
                if (dd >= 0 && dd < DD) {
                    const int a = base + dd * HW;
                    const h4 q = ws0123[a];
                    v0 = __half2float(q.lo.x);
                    v1 = __half2float(q.lo.y);
                    v2 = __half2float(q.hi.x);
                    v3 = __half2float(q.hi.y);
                    v4 = __half2float(ws4[a]);
                }
                run0 += v0 - ring[0][jj]; ring[0][jj] = v0;
                run1 += v1 - ring[1][jj]; ring[1][jj] = v1;
                run2 += v2 - ring[2][jj]; ring[2][jj] = v2;
                run3 += v3 - ring[3][jj]; ring[3][jj] = v3;
                run4 += v4 - ring[4][jj]; ring[4][jj] = v4;

                if (s >= 8) {
                    const int d = d0 + s - 8;
                    const float cD  = (float)(min(d + 4, DD - 1) - max(d - 4, 0) + 1);
                    const float cnt = cHW * cD;
                    // reconstruct uncentered box sums (exact algebra)
                    const float Is  = run0 + 0.5f * cnt;
                    const float Js  = run1 + 0.5f * cnt;
                    const float I2  = run2 + run0 + 0.25f * cnt;
                    const float J2  = run3 + run1 + 0.25f * cnt;
                    const float IJ  = run4 + 0.5f * (run0 + run1) + 0.25f * cnt;
                    const float uI = Is * inv, uJ = Js * inv;
                    const float cross = IJ - uI * Js;
                    const float Iv = fmaxf(I2 - uI * Is, 1e-5f);
                    const float Jv = fmaxf(J2 - uJ * Js, 1e-5f);
                    acc += cross * cross / (Iv * Jv + 1e-5f);
                }
            }
        }
    }

    // ---- block reduction, one fp32 atomic per block ----
    __shared__ float wred[4];
    #pragma unroll
    for (int off = 32; off > 0; off >>= 1)
        acc += __shfl_down(acc, off, 64);
    const int lane = threadIdx.x & 63, wid = threadIdx.x >> 6;
    if (lane == 0) wred[wid] = acc;
    __syncthreads();
    if (threadIdx.x == 0)
        atomicAdd(outp, -(wred[0] + wred[1] + wred[2] + wred[3]));
}

// ---------------------------------------------------------------------------
// Fallback (ws too small): R9's fused kernel, known-passing at ~134 us.
// ---------------------------------------------------------------------------
constexpr int FTW = 16, FTH = 16, FHLO = FTH + 8;
constexpr int FCH = 20, FNCH = DD / FCH, FNSL = FCH + 8, FNR = FNSL / 2;

__global__ __launch_bounds__(256, 4)
void ncc_fused(const float* __restrict__ I, const float* __restrict__ J,
               float* __restrict__ outp)
{
    __shared__ float4 sws[2][FHLO][FTW + 1];
    __shared__ float  sw4[2][FHLO][FTW + 1];
    __shared__ float  wred[4];

    const int tid = threadIdx.x;
    const int w0 = blockIdx.x * FTW, h0 = blockIdx.y * FTH;
    const int z = blockIdx.z, n = z / FNCH, d0 = (z % FNCH) * FCH;
    const int lane = tid & 63, wid = tid >> 6;
    const int oh = tid >> 4, ow = tid & 15;
    const bool ajob = (tid < 192);
    const int sl = tid / 96, rj = tid - sl * 96;
    const int arow = rj >> 2, awg = rj & 3;
    const int agh = h0 + arow - 4, agws = w0 + awg * 4 - 4;
    const bool ahok = (agh >= 0) && (agh < HH);

    float rbuf[5][9];
    #pragma unroll
    for (int p = 0; p < 5; ++p)
        #pragma unroll
        for (int q = 0; q < 9; ++q) rbuf[p][q] = 0.f;
    float run0 = 0.f, run1 = 0.f, run2 = 0.f, run3 = 0.f, run4 = 0.f;
    float acc = 0.f;
    const float inv = 1.0f / 729.0f;

    #pragma unroll 1
    for (int g = 0; g < 2; ++g) {
        #pragma unroll
        for (int r = 0; r < 9; ++r) {
            const int rr = g * 9 + r;
            if (rr < FNR) {
                const int s0 = 2 * rr, dd0 = d0 - 4 + s0;
                if (ajob) {
                    const int dd = dd0 + sl;
                    if (dd >= 0 && dd < DD) {
                        float a[12], b[12];
                        const int rbase = (n * DD + dd) * HW + agh * WW;
                        #pragma unroll
                        for (int c = 0; c < 3; ++c) {
                            const int gw = agws + 4 * c;
                            float4 va = make_float4(0.f, 0.f, 0.f, 0.f), vb = va;
                            if (ahok && gw >= 0 && gw < WW) {
                                va = *(const float4*)(I + rbase + gw);
                                vb = *(const float4*)(J + rbase + gw);
                            }
                            *(float4*)&a[4 * c] = va;
                            *(float4*)&b[4 * c] = vb;
                        }
                        float S0[4], S1[4], S2[4], S3[4], S4[4], f[12];
                        slide4(a, S0);
                        slide4(b, S1);
                        #pragma unroll
                        for (int i = 0; i < 12; ++i) f[i] = a[i] * a[i];
                        slide4(f, S2);
                        #pragma unroll
                        for (int i = 0; i < 12; ++i) f[i] = b[i] * b[i];
                        slide4(f, S3);
                        #pragma unroll
                        for (int i = 0; i < 12; ++i) f[i] = a[i] * b[i];
                        slide4(f, S4);
                        #pragma unroll
                        for (int t = 0; t < 4; ++t) {
                            sws[sl][arow][awg * 4 + t] =
                                make_float4(S0[t], S1[t], S2[t], S3[t]);
                            sw4[sl][arow][awg * 4 + t] = S4[t];
                        }
                    }
                }
                __syncthreads();
                #pragma unroll
                for (int half = 0; half < 2; ++half) {
                    const int ddx = dd0 + half, sx = s0 + half;
                    float t0 = 0.f, t1 = 0.f, t2 = 0.f, t3 = 0.f, t4 = 0.f;
                    if (ddx >= 0 && ddx < DD) {
                        #pragma unroll
                        for (int q = 0; q < 9; ++q) {
                            const float4 v = sws[half][oh + q][ow];
                            t0 += v.x; t1 += v.y; t2 += v.z; t3 += v.w;
                            t4 += sw4[half][oh + q][ow];
                        }
                    }
                    const int jj = (2 * r + half) % 9;
                    run0 += t0 - rbuf[0][jj]; rbuf[0][jj] = t0;
                    run1 += t1 - rbuf[1][jj]; rbuf[1][jj] = t1;
                    run2 += t2 - rbuf[2][jj]; rbuf[2][jj] = t2;
                    run3 += t3 - rbuf[3][jj]; rbuf[3][jj] = t3;
                    run4 += t4 - rbuf[4][jj]; rbuf[4][jj] = t4;
                    if (sx >= 8) {
                        const float uI = run0 * inv, uJ = run1 * inv;
                        const float cross = run4 - uI * run1;
                        const float Iv = fmaxf(run2 - uI * run0, 1e-5f);
                        const float Jv = fmaxf(run3 - uJ * run1, 1e-5f);
                        acc += cross * cross / (Iv * Jv + 1e-5f);
                    }
                }
                __syncthreads();
            }
        }
    }
    #pragma unroll
    for (int off = 32; off > 0; off >>= 1)
        acc += __shfl_down(acc, off, 64);
    if (lane == 0) wred[wid] = acc;
    __syncthreads();
    if (tid == 0)
        atomicAdd(outp, -(wred[0] + wred[1] + wred[2] + wred[3]));
}

extern "C" void kernel_launch(void* const* d_in, const int* in_sizes, int n_in,
                              void* d_out, int out_size, void* d_ws, size_t ws_size,
                              hipStream_t stream)
{
    const float* I = (const float*)d_in[0];   // y_true
    const float* J = (const float*)d_in[1];   // y_pred
    float* out = (float*)d_out;

    const size_t need = (size_t)10 * VOX;     // 98.3 MB (8+2 B per voxel)
    if (ws_size >= need) {
        h4* ws0123 = (h4*)d_ws;
        __half* ws4 = (__half*)(ws0123 + (size_t)VOX);
        dim3 g1(WW / P1TW, HH / P1TH, ND * DD);   // 5 x 6 x 320 = 9600
        ncc_pass1<<<g1, 256, 0, stream>>>(I, J, ws0123, ws4, out);
        dim3 g2(ND * HW / 256, DD / P2CH);        // 240 x 4 = 960
        ncc_pass2<<<g2, 256, 0, stream>>>(ws0123, ws4, out);
    } else {
        hipMemsetAsync(out, 0, sizeof(float), stream);
        dim3 grid(WW / FTW, HH / FTH, ND * FNCH); // 10 x 12 x 16
        ncc_fused<<<grid, 256, 0, stream>>>(I, J, out);
    }
}

// Round 3
// 166.410 us; speedup vs baseline: 1.1618x; 1.0847x over previous
//
#include <hip/hip_runtime.h>
#include <hip/hip_fp16.h>

// NCC loss, v10: SINGLE fused kernel, D-streaming with the 9-slot ring held
// in LDS as centered-fp16 (exactly the quantity v7-v9 stored in the global
// ws — same rounding, proven absmax 0).
// Why: v9 arithmetic shows fixed harness overhead >= 57us (total 180.5 =
// pass1 62.0 + pass2(<61.5) + overhead). Two-pass spends 96MB ws writes +
// ~118MB ws reads + an inter-kernel drain. Fusing deletes all of it for
// 1.2x D-halo recompute.
// Geometry: 512 thr, 32x16 tile (512 columns = 1 ring/thread), FCH=40 ->
// 480 blocks; in-plane fetch redundancy 1.875, D redundancy 1.2 ->
// FETCH ~177MB. LDS 77.8KB/block -> 2 blocks/CU with launch_bounds(512,4).
#define ND 2
#define DD 160
#define HH 192
#define WW 160
#define HW (HH * WW)
#define DHW (DD * HH * WW)

constexpr int TW  = 32;            // tile width  (outputs)
constexpr int TH  = 16;            // tile height (outputs) -> 512 columns
constexpr int HLO = TH + 8;        // 24 rows incl. H halo
constexpr int FCH = 40;            // d outputs per block
constexpr int NCH = DD / FCH;      // 4 chunks
constexpr int NSL = FCH + 8;       // 48 slices streamed
constexpr int NR  = NSL / 2;       // 24 rounds, 2 slices each

struct alignas(8) h4 { __half2 lo, hi; };

__device__ __forceinline__ void slide4(const float x[12], float S[4]) {
    float f = ((x[0] + x[1]) + (x[2] + x[3]))
            + ((x[4] + x[5]) + (x[6] + x[7])) + x[8];
    S[0] = f;
    f += x[9]  - x[0]; S[1] = f;
    f += x[10] - x[1]; S[2] = f;
    f += x[11] - x[2]; S[3] = f;
}

__global__ __launch_bounds__(512, 4)
void ncc_fused2(const float* __restrict__ I, const float* __restrict__ J,
                float* __restrict__ outp)
{
    // stage-A output: centered W-sums of (I,J,II,JJ) + IJ, 2 slices
    __shared__ float4 sws[2][HLO][TW + 1];          // 25,344 B
    __shared__ float  sw4[2][HLO][TW + 1];          //  6,336 B
    // D-ring: last 9 slices' centered HW-sums, fp16 (matches proven ws fmt)
    __shared__ h4     ring4[9][512];                // 36,864 B
    __shared__ __half ring1[9][512];                //  9,216 B
    __shared__ float  wred[8];

    const int tid = threadIdx.x;
    const int w0  = blockIdx.x * TW;                // 0..128
    const int h0  = blockIdx.y * TH;                // 0..176
    const int z   = blockIdx.z;                     // 0..7
    const int n   = z >> 2;
    const int d0  = (z & 3) * FCH;

    // ---- stage-A role: 384 jobs = 2 slices x 24 rows x 8 groups ----
    const bool ajob = (tid < 384);
    const int  sl   = tid / 192;                    // slice-of-round (0/1)
    const int  rj   = tid - sl * 192;
    const int  arow = rj >> 3;                      // 0..23
    const int  awg  = rj & 7;                       // 0..7
    const int  agh  = h0 + arow - 4;
    const bool ahok = (agh >= 0) && (agh < HH);
    const int  agws = w0 + awg * 4 - 4;

    // ---- stage-B role: one (h,w) column per thread ----
    const int oh = tid >> 5;                        // 0..15
    const int ow = tid & 31;                        // 0..31
    const int h  = h0 + oh, w = w0 + ow;
    const float cW  = (float)(min(w + 4, WW - 1) - max(w - 4, 0) + 1);
    const float cH  = (float)(min(h + 4, HH - 1) - max(h - 4, 0) + 1);
    const float cHW = cW * cH;

    // zero this thread's ring slots (only this thread ever touches them)
    {
        h4 zz; zz.lo = __floats2half2_rn(0.f, 0.f); zz.hi = zz.lo;
        const __half z1 = __float2half(0.f);
        #pragma unroll
        for (int q = 0; q < 9; ++q) { ring4[q][tid] = zz; ring1[q][tid] = z1; }
    }

    float run0 = 0.f, run1 = 0.f, run2 = 0.f, run3 = 0.f, run4 = 0.f;
    float acc = 0.f;
    const float inv = 1.0f / 729.0f;

    #pragma unroll 1
    for (int g = 0; g < 3; ++g) {                   // 3 x 9 = 27 >= NR
        #pragma unroll
        for (int r = 0; r < 9; ++r) {
            const int rr = g * 9 + r;
            if (rr < NR) {
                const int s0  = 2 * rr;
                const int dd0 = d0 - 4 + s0;
                // ---- stage A: W-sums for slices dd0, dd0+1 ----
                if (ajob) {
                    const int dd = dd0 + sl;
                    if (dd >= 0 && dd < DD) {
                        const int rbase = (n * DD + dd) * HW + agh * WW;
                        float a[12], b[12];
                        #pragma unroll
                        for (int c = 0; c < 3; ++c) {
                            const int gw = agws + 4 * c;
                            float4 va = make_float4(0.f, 0.f, 0.f, 0.f), vb = va;
                            if (ahok && gw >= 0 && gw < WW) {
                                va = *(const float4*)(I + rbase + gw);
                                vb = *(const float4*)(J + rbase + gw);
                                va.x -= 0.5f; va.y -= 0.5f; va.z -= 0.5f; va.w -= 0.5f;
                                vb.x -= 0.5f; vb.y -= 0.5f; vb.z -= 0.5f; vb.w -= 0.5f;
                            }
                            *(float4*)&a[4 * c] = va;
                            *(float4*)&b[4 * c] = vb;
                        }
                        float S0[4], S1[4], S2[4], S3[4], S4[4], f[12];
                        slide4(a, S0);
                        slide4(b, S1);
                        #pragma unroll
                        for (int i = 0; i < 12; ++i) f[i] = a[i] * a[i];
                        slide4(f, S2);
                        #pragma unroll
                        for (int i = 0; i < 12; ++i) f[i] = b[i] * b[i];
                        slide4(f, S3);
                        #pragma unroll
                        for (int i = 0; i < 12; ++i) f[i] = a[i] * b[i];
                        slide4(f, S4);
                        #pragma unroll
                        for (int t = 0; t < 4; ++t) {
                            sws[sl][arow][awg * 4 + t] =
                                make_float4(S0[t], S1[t], S2[t], S3[t]);
                            sw4[sl][arow][awg * 4 + t] = S4[t];
                        }
                    }
                }
                __syncthreads();
                // ---- stage B: HW-sum taps + fp16 ring + cc ----
                #pragma unroll
                for (int half = 0; half < 2; ++half) {
                    const int s   = s0 + half;
                    const int ddx = dd0 + half;
                    float t0 = 0.f, t1 = 0.f, t2 = 0.f, t3 = 0.f, t4 = 0.f;
                    if (ddx >= 0 && ddx < DD) {
                        #pragma unroll
                        for (int q = 0; q < 9; ++q) {
                            const float4 v = sws[half][oh + q][ow];
                            t0 += v.x; t1 += v.y; t2 += v.z; t3 += v.w;
                            t4 += sw4[half][oh + q][ow];
                        }
                    }
                    // round to fp16 (same rounding as the proven global ws)
                    h4 nh;
                    nh.lo = __floats2half2_rn(t0, t1);
                    nh.hi = __floats2half2_rn(t2, t3);
                    const __half n4 = __float2half(t4);
                    const int jj = (2 * r + half) % 9;   // compile-time const
                    const h4     po = ring4[jj][tid];
                    const __half p4 = ring1[jj][tid];
                    run0 += __half2float(nh.lo.x) - __half2float(po.lo.x);
                    run1 += __half2float(nh.lo.y) - __half2float(po.lo.y);
                    run2 += __half2float(nh.hi.x) - __half2float(po.hi.x);
                    run3 += __half2float(nh.hi.y) - __half2float(po.hi.y);
                    run4 += __half2float(n4)      - __half2float(p4);
                    ring4[jj][tid] = nh;
                    ring1[jj][tid] = n4;
                    if (s >= 8) {
                        const int d = d0 + s - 8;
                        const float cD  = (float)(min(d + 4, DD - 1) - max(d - 4, 0) + 1);
                        const float cnt = cHW * cD;
                        // reconstruct uncentered box sums (exact algebra, from
                        // the verified pass2)
                        const float Is = run0 + 0.5f * cnt;
                        const float Js = run1 + 0.5f * cnt;
                        const float I2 = run2 + run0 + 0.25f * cnt;
                        const float J2 = run3 + run1 + 0.25f * cnt;
                        const float IJ = run4 + 0.5f * (run0 + run1) + 0.25f * cnt;
                        const float uI = Is * inv, uJ = Js * inv;
                        const float cross = IJ - uI * Js;
                        const float Iv = fmaxf(I2 - uI * Is, 1e-5f);
                        const float Jv = fmaxf(J2 - uJ * Js, 1e-5f);
                        acc += cross * cross / (Iv * Jv + 1e-5f);
                    }
                }
                __syncthreads();
            }
        }
    }

    // ---- block reduction, one fp32 atomic per block ----
    #pragma unroll
    for (int off = 32; off > 0; off >>= 1)
        acc += __shfl_down(acc, off, 64);
    const int lane = tid & 63, wid = tid >> 6;
    if (lane == 0) wred[wid] = acc;
    __syncthreads();
    if (tid == 0) {
        float s = 0.f;
        #pragma unroll
        for (int i = 0; i < 8; ++i) s += wred[i];
        atomicAdd(outp, -s);
    }
}

extern "C" void kernel_launch(void* const* d_in, const int* in_sizes, int n_in,
                              void* d_out, int out_size, void* d_ws, size_t ws_size,
                              hipStream_t stream)
{
    const float* I = (const float*)d_in[0];   // y_true
    const float* J = (const float*)d_in[1];   // y_pred
    float* out = (float*)d_out;

    hipMemsetAsync(out, 0, sizeof(float), stream);
    dim3 grid(WW / TW, HH / TH, ND * NCH);    // 5 x 12 x 8 = 480 blocks
    ncc_fused2<<<grid, 512, 0, stream>>>(I, J, out);
}